// Round 1
// baseline (116.823 us; speedup 1.0000x reference)
//
#include <hip/hip_runtime.h>
#include <hip/hip_bf16.h>

#define BB 8
#define NN 16384
#define SS 1024
#define NSMP 64
#define DD 128
#define R2 0.04f
#define EPSV 1e-5f

typedef _Float16 half2t __attribute__((ext_vector_type(2)));
typedef _Float16 half8t __attribute__((ext_vector_type(8)));
typedef float f32x4 __attribute__((ext_vector_type(4)));

// ---- workspace layout (bytes) ----
#define O_PT    0ull                 // pointsT fp16: 8*16384*128*2 = 33,554,432
#define O_Y0    33554432ull          // y0 fp16: 524288*128*2 = 134,217,728
#define O_Y1    167772160ull         // y1 fp16: 134,217,728
#define O_IDX   301989888ull         // idx int32: 8192*64*4 = 2,097,152
#define O_MAXB  304087040ull         // 8192*256*4 = 8,388,608
#define O_MINB  312475648ull         // 8,388,608
#define O_W0T   320864256ull         // W0h fp16 [128][136] = 34,816 (slot 67,072)
#define O_W1T   320931328ull         // W1h fp16 [128][136] = 34,816 (slot 65,536)
#define O_W2T   320996864ull         // W2h fp16 [256][136] = 69,632 (slot 131,072)
#define O_PS0   321127936ull         // 128*256*4 = 131,072
#define O_PQ0   321259008ull
#define O_PS1   321390080ull
#define O_PQ1   321521152ull
#define O_PS2   321652224ull         // 256*256*4 = 262,144
#define O_PQ2   321914368ull
#define O_SC0   322176512ull
#define O_SH0   322177024ull
#define O_SC1   322177536ull
#define O_SH1   322178048ull
#define O_SC2   322178560ull
#define O_SH2   322179584ull
#define WS_NEEDED 322180608ull
#define PART_BYTES 1048576ull

#define OUT_XYZ 0
#define OUT_FEAT 24576
#define OUT_FPS (24576 + 2097152)

// points [B,D,N] fp32 -> pointsT [B,N,D] fp16
__global__ __launch_bounds__(256) void k_transpose_pts(const float* __restrict__ pts,
                                                       _Float16* __restrict__ ptsT) {
  __shared__ float tile[32][33];
  int b = blockIdx.z;
  int n0 = blockIdx.x * 32, c0 = blockIdx.y * 32;
  int tx = threadIdx.x, ty = threadIdx.y;
#pragma unroll
  for (int k = 0; k < 4; k++) {
    int c = c0 + ty + k * 8;
    tile[ty + k * 8][tx] = pts[((size_t)b * DD + c) * NN + n0 + tx];
  }
  __syncthreads();
#pragma unroll
  for (int k = 0; k < 4; k++) {
    int n = n0 + ty + k * 8;
    ptsT[((size_t)b * NN + n) * DD + c0 + tx] = (_Float16)tile[tx][ty + k * 8];
  }
}

// weights -> fp16, [out][in] layout, stride 136, zero-padded.
// W0 channels remapped: xh has feats at c=0..127, relxyz at 128..130
__global__ __launch_bounds__(256) void k_wt(const float* __restrict__ W0, const float* __restrict__ W1,
                                            const float* __restrict__ W2, _Float16* __restrict__ W0h,
                                            _Float16* __restrict__ W1h, _Float16* __restrict__ W2h) {
  int id = blockIdx.x * 256 + threadIdx.x;
  const int T0 = 128 * 136, T1 = 128 * 136, T2 = 256 * 136;
  if (id < T0) {
    int o = id / 136, c = id % 136;
    float v = 0.f;
    if (c < 131) {
      int c0 = (c < 128) ? (c + 3) : (c - 128);
      v = W0[o * 131 + c0];
    }
    W0h[id] = (_Float16)v;
  } else if (id < T0 + T1) {
    int j = id - T0;
    int o = j / 136, c = j % 136;
    W1h[j] = (_Float16)((c < 128) ? W1[o * 128 + c] : 0.f);
  } else if (id < T0 + T1 + T2) {
    int j = id - T0 - T1;
    int o = j / 136, c = j % 136;
    W2h[j] = (_Float16)((c < 128) ? W2[o * 128 + c] : 0.f);
  }
}

__global__ __launch_bounds__(256) void k_newxyz(const float* __restrict__ xyz, const int* __restrict__ fps,
                                                float* __restrict__ out) {
  int id = blockIdx.x * 256 + threadIdx.x;  // B*S
  int fi = fps[id];
  int b = id >> 10;
  const float* p = xyz + ((size_t)b * NN + fi) * 3;
  float* o = out + OUT_XYZ + (size_t)id * 3;
  o[0] = p[0]; o[1] = p[1]; o[2] = p[2];
  out[OUT_FPS + id] = (float)fi;
}

// one wave per (b,s): first-NS valid indices in ascending n, pad with first valid
__global__ __launch_bounds__(256) void k_ballq(const float* __restrict__ xyz, const int* __restrict__ fps,
                                               int* __restrict__ idxb) {
  int w = (blockIdx.x * 256 + threadIdx.x) >> 6;
  int lane = threadIdx.x & 63;
  int b = w >> 10;
  int fi = fps[w];
  const float* cp = xyz + ((size_t)b * NN + fi) * 3;
  float cx = cp[0], cy = cp[1], cz = cp[2];
  // match numpy association: (cx^2 + cy^2) + cz^2
  float A = __fadd_rn(__fadd_rn(__fmul_rn(cx, cx), __fmul_rn(cy, cy)), __fmul_rn(cz, cz));
  const float* xb = xyz + (size_t)b * NN * 3;
  int cnt = 0, firstn = -1;
  int* myidx = idxb + (size_t)w * NSMP;
  for (int nb = 0; nb < NN && cnt < NSMP; nb += 64) {
    int n = nb + lane;
    float px = xb[n * 3], py = xb[n * 3 + 1], pz = xb[n * 3 + 2];
    float Bv = __fadd_rn(__fadd_rn(__fmul_rn(px, px), __fmul_rn(py, py)), __fmul_rn(pz, pz));
    float dot = __fadd_rn(__fadd_rn(__fmul_rn(cx, px), __fmul_rn(cy, py)), __fmul_rn(cz, pz));
    float d = __fsub_rn(__fadd_rn(A, Bv), __fmul_rn(2.0f, dot));
    bool valid = !(d > R2);
    unsigned long long mask = __ballot(valid);
    if (firstn < 0 && mask) firstn = nb + __builtin_ctzll(mask);
    int prefix = __popcll(mask & ((1ull << lane) - 1ull));
    int pos = cnt + prefix;
    if (valid && pos < NSMP) myidx[pos] = n;
    cnt += __popcll(mask);
    if (cnt > NSMP) cnt = NSMP;
  }
  if (lane >= cnt) myidx[lane] = firstn;
}

// layer0: gather -> y0 = W0*x + b0 via MFMA ; per-channel sum/sumsq partials
__global__ __launch_bounds__(256, 2) void k_mlp0(const float* __restrict__ xyz,
                                                 const _Float16* __restrict__ ptsT,
                                                 const int* __restrict__ fps, const int* __restrict__ idxb,
                                                 const _Float16* __restrict__ W0h, const float* __restrict__ b0,
                                                 _Float16* __restrict__ y0, float* __restrict__ psum,
                                                 float* __restrict__ psq) {
  __shared__ _Float16 xh[64 * 136];  // fp16 input tile, stride 136 (272B, bank-spread + 16B aligned)
  __shared__ float xs[64 * 133];     // fp32 y tile for store+stats (layout as before)
  __shared__ float rbuf[128 * 2];
  __shared__ int smidx[64];
  __shared__ float smc[3];
  int t = threadIdx.x;
  int bs = blockIdx.x;
  int b = bs >> 10;
  if (t < 64) smidx[t] = idxb[(size_t)bs * 64 + t];
  if (t < 3) {
    int fi = fps[bs];
    smc[t] = xyz[((size_t)b * NN + fi) * 3 + t];
  }
  __syncthreads();
  {
    int row = t >> 2, q = t & 3;
    int n = smidx[row];
    const half8t* src = (const half8t*)(ptsT + ((size_t)b * NN + n) * DD);
#pragma unroll
    for (int i = 0; i < 4; i++) {
      int j = q + i * 4;  // 16 chunks of 8 halfs per row
      *(half8t*)(xh + row * 136 + j * 8) = src[j];
    }
  }
  if (t < 64) {
    int n = smidx[t];
    const float* p = xyz + ((size_t)b * NN + n) * 3;
    xh[t * 136 + 128] = (_Float16)(p[0] - smc[0]);
    xh[t * 136 + 129] = (_Float16)(p[1] - smc[1]);
    xh[t * 136 + 130] = (_Float16)(p[2] - smc[2]);
  }
  __syncthreads();
  int lane = t & 63;
  int m0 = __builtin_amdgcn_readfirstlane((t >> 6) * 16);  // wave's 16-row slab
  int lr = lane & 15, lk = lane >> 4;
  half8t afr[4];
#pragma unroll
  for (int kt = 0; kt < 4; kt++)
    afr[kt] = *(const half8t*)(xh + (m0 + lr) * 136 + kt * 32 + lk * 8);
  f32x4 acc[8];
#pragma unroll
  for (int nt = 0; nt < 8; nt++) {
    float bv = b0[nt * 16 + lr];
    f32x4 cv = {bv, bv, bv, bv};
    acc[nt] = cv;
  }
#pragma unroll
  for (int kt = 0; kt < 4; kt++) {
#pragma unroll
    for (int nt = 0; nt < 8; nt++) {
      half8t bw = *(const half8t*)(W0h + (nt * 16 + lr) * 136 + kt * 32 + lk * 8);
      acc[nt] = __builtin_amdgcn_mfma_f32_16x16x32_f16(afr[kt], bw, acc[nt], 0, 0, 0);
    }
  }
  // relative-xyz channels (c=128..130) on the VALU; D rows for this lane: m0+lk*4+r
  {
    float xr[4][3];
#pragma unroll
    for (int r = 0; r < 4; r++) {
      int m = m0 + lk * 4 + r;
      xr[r][0] = (float)xh[m * 136 + 128];
      xr[r][1] = (float)xh[m * 136 + 129];
      xr[r][2] = (float)xh[m * 136 + 130];
    }
#pragma unroll
    for (int nt = 0; nt < 8; nt++) {
      const _Float16* wp = W0h + (nt * 16 + lr) * 136 + 128;
      float w0 = (float)wp[0], w1 = (float)wp[1], w2 = (float)wp[2];
#pragma unroll
      for (int r = 0; r < 4; r++)
        acc[nt][r] += xr[r][0] * w0 + xr[r][1] * w1 + xr[r][2] * w2;
    }
  }
  // dump accs to xs (D layout: row=(lane>>4)*4+reg, col=lane&15)
#pragma unroll
  for (int nt = 0; nt < 8; nt++)
#pragma unroll
    for (int r = 0; r < 4; r++)
      xs[(m0 + lk * 4 + r) * 133 + nt * 16 + lr] = acc[nt][r];
  __syncthreads();
  {
    _Float16* dst = y0 + (size_t)bs * 8192;
#pragma unroll
    for (int i = 0; i < 16; i++) {
      int flat = i * 512 + 2 * t;
      int row = flat >> 7, col = flat & 127;
      half2t h;
      h[0] = (_Float16)xs[row * 133 + col];
      h[1] = (_Float16)xs[row * 133 + col + 1];
      *(half2t*)(dst + flat) = h;
    }
  }
  {
    int col = t & 127, half = t >> 7;
    float s = 0.f, q = 0.f;
#pragma unroll 4
    for (int r = half * 32; r < half * 32 + 32; r++) {
      float v = xs[r * 133 + col];
      s += v;
      q = fmaf(v, v, q);
    }
    if (half) { rbuf[col * 2] = s; rbuf[col * 2 + 1] = q; }
    __syncthreads();
    if (!half) {
      s += rbuf[col * 2];
      q += rbuf[col * 2 + 1];
      int slot = bs & 255;
      atomicAdd(&psum[col * 256 + slot], s);
      atomicAdd(&psq[col * 256 + slot], q);
    }
  }
}

// layer1: x1 = relu(a0*y0+c0) ; y1 = W1*x1 + b1 via MFMA ; partials
__global__ __launch_bounds__(256, 2) void k_mlp1(const _Float16* __restrict__ y0,
                                                 const float* __restrict__ sc, const float* __restrict__ sh,
                                                 const _Float16* __restrict__ W1h, const float* __restrict__ b1,
                                                 _Float16* __restrict__ y1, float* __restrict__ psum,
                                                 float* __restrict__ psq) {
  __shared__ _Float16 xh[64 * 136];
  __shared__ float xs[64 * 133];
  __shared__ float rbuf[128 * 2];
  int t = threadIdx.x;
  int bs = blockIdx.x;
  {
    int colb = (2 * t) & 127;
    float a0 = sc[colb], a1 = sc[colb + 1];
    float c0 = sh[colb], c1 = sh[colb + 1];
    const _Float16* src = y0 + (size_t)bs * 8192;
#pragma unroll
    for (int i = 0; i < 16; i++) {
      int flat = i * 512 + 2 * t;
      int row = flat >> 7, col = flat & 127;
      half2t h = *(const half2t*)(src + flat);
      half2t o;
      o[0] = (_Float16)fmaxf(fmaf((float)h[0], a0, c0), 0.f);
      o[1] = (_Float16)fmaxf(fmaf((float)h[1], a1, c1), 0.f);
      *(half2t*)(xh + row * 136 + col) = o;
    }
  }
  __syncthreads();
  int lane = t & 63;
  int m0 = __builtin_amdgcn_readfirstlane((t >> 6) * 16);
  int lr = lane & 15, lk = lane >> 4;
  half8t afr[4];
#pragma unroll
  for (int kt = 0; kt < 4; kt++)
    afr[kt] = *(const half8t*)(xh + (m0 + lr) * 136 + kt * 32 + lk * 8);
  f32x4 acc[8];
#pragma unroll
  for (int nt = 0; nt < 8; nt++) {
    float bv = b1[nt * 16 + lr];
    f32x4 cv = {bv, bv, bv, bv};
    acc[nt] = cv;
  }
#pragma unroll
  for (int kt = 0; kt < 4; kt++) {
#pragma unroll
    for (int nt = 0; nt < 8; nt++) {
      half8t bw = *(const half8t*)(W1h + (nt * 16 + lr) * 136 + kt * 32 + lk * 8);
      acc[nt] = __builtin_amdgcn_mfma_f32_16x16x32_f16(afr[kt], bw, acc[nt], 0, 0, 0);
    }
  }
#pragma unroll
  for (int nt = 0; nt < 8; nt++)
#pragma unroll
    for (int r = 0; r < 4; r++)
      xs[(m0 + lk * 4 + r) * 133 + nt * 16 + lr] = acc[nt][r];
  __syncthreads();
  {
    _Float16* dst = y1 + (size_t)bs * 8192;
#pragma unroll
    for (int i = 0; i < 16; i++) {
      int flat = i * 512 + 2 * t;
      int row = flat >> 7, col = flat & 127;
      half2t h;
      h[0] = (_Float16)xs[row * 133 + col];
      h[1] = (_Float16)xs[row * 133 + col + 1];
      *(half2t*)(dst + flat) = h;
    }
  }
  {
    int col = t & 127, half = t >> 7;
    float s = 0.f, q = 0.f;
#pragma unroll 4
    for (int r = half * 32; r < half * 32 + 32; r++) {
      float v = xs[r * 133 + col];
      s += v;
      q = fmaf(v, v, q);
    }
    if (half) { rbuf[col * 2] = s; rbuf[col * 2 + 1] = q; }
    __syncthreads();
    if (!half) {
      s += rbuf[col * 2];
      q += rbuf[col * 2 + 1];
      int slot = bs & 255;
      atomicAdd(&psum[col * 256 + slot], s);
      atomicAdd(&psq[col * 256 + slot], q);
    }
  }
}

// layer2: x2 = relu(a1*y1+c1) ; y2 = W2*x2 + b2 via MFMA (256 ch, NOT stored);
// per-(bs,o) max & min over the 64 neighbors + global partials
__global__ __launch_bounds__(256, 2) void k_mlp2(const _Float16* __restrict__ y1,
                                                 const float* __restrict__ sc, const float* __restrict__ sh,
                                                 const _Float16* __restrict__ W2h, const float* __restrict__ b2,
                                                 float* __restrict__ maxb, float* __restrict__ minb,
                                                 float* __restrict__ psum, float* __restrict__ psq) {
  __shared__ _Float16 xh[64 * 136];
  __shared__ float xs[64 * 133];
  __shared__ float rbuf[128 * 4];
  int t = threadIdx.x;
  int bs = blockIdx.x;
  {
    int colb = (2 * t) & 127;
    float a0 = sc[colb], a1 = sc[colb + 1];
    float c0 = sh[colb], c1 = sh[colb + 1];
    const _Float16* src = y1 + (size_t)bs * 8192;
#pragma unroll
    for (int i = 0; i < 16; i++) {
      int flat = i * 512 + 2 * t;
      int row = flat >> 7, col = flat & 127;
      half2t h = *(const half2t*)(src + flat);
      half2t o;
      o[0] = (_Float16)fmaxf(fmaf((float)h[0], a0, c0), 0.f);
      o[1] = (_Float16)fmaxf(fmaf((float)h[1], a1, c1), 0.f);
      *(half2t*)(xh + row * 136 + col) = o;
    }
  }
  __syncthreads();
  int lane = t & 63;
  int m0 = __builtin_amdgcn_readfirstlane((t >> 6) * 16);
  int lr = lane & 15, lk = lane >> 4;
  half8t afr[4];
#pragma unroll
  for (int kt = 0; kt < 4; kt++)
    afr[kt] = *(const half8t*)(xh + (m0 + lr) * 136 + kt * 32 + lk * 8);
  f32x4 acc[16];
#pragma unroll
  for (int nt = 0; nt < 16; nt++) {
    float bv = b2[nt * 16 + lr];
    f32x4 cv = {bv, bv, bv, bv};
    acc[nt] = cv;
  }
#pragma unroll
  for (int kt = 0; kt < 4; kt++) {
#pragma unroll
    for (int nt = 0; nt < 16; nt++) {
      half8t bw = *(const half8t*)(W2h + (nt * 16 + lr) * 136 + kt * 32 + lk * 8);
      acc[nt] = __builtin_amdgcn_mfma_f32_16x16x32_f16(afr[kt], bw, acc[nt], 0, 0, 0);
    }
  }
  // two 128-col phases through xs, epilogue unchanged
  for (int ph = 0; ph < 2; ph++) {
#pragma unroll
    for (int nt = 0; nt < 8; nt++)
#pragma unroll
      for (int r = 0; r < 4; r++)
        xs[(m0 + lk * 4 + r) * 133 + nt * 16 + lr] = acc[ph * 8 + nt][r];
    __syncthreads();
    {
      int col = t & 127, half = t >> 7;
      float s = 0.f, q = 0.f, mx = -3.4e38f, mn = 3.4e38f;
#pragma unroll 4
      for (int r = half * 32; r < half * 32 + 32; r++) {
        float v = xs[r * 133 + col];
        s += v;
        q = fmaf(v, v, q);
        mx = fmaxf(mx, v);
        mn = fminf(mn, v);
      }
      if (half) {
        rbuf[col * 4] = s; rbuf[col * 4 + 1] = q;
        rbuf[col * 4 + 2] = mx; rbuf[col * 4 + 3] = mn;
      }
      __syncthreads();
      if (!half) {
        s += rbuf[col * 4];
        q += rbuf[col * 4 + 1];
        mx = fmaxf(mx, rbuf[col * 4 + 2]);
        mn = fminf(mn, rbuf[col * 4 + 3]);
        int o = ph * 128 + col;
        maxb[(size_t)bs * 256 + o] = mx;
        minb[(size_t)bs * 256 + o] = mn;
        int slot = bs & 255;
        atomicAdd(&psum[o * 256 + slot], s);
        atomicAdd(&psq[o * 256 + slot], q);
      }
    }
    __syncthreads();
  }
}

// fold BN stats into per-channel affine: a = g*rsqrt(var+eps); c = be - mean*a
__global__ __launch_bounds__(256) void k_fin(const float* __restrict__ psum, const float* __restrict__ psq,
                                             const float* __restrict__ g, const float* __restrict__ be,
                                             float* __restrict__ sc, float* __restrict__ sh, int nch) {
  int o = threadIdx.x;
  if (o >= nch) return;
  float s = 0.f, q = 0.f;
  for (int k = 0; k < 256; k++) {
    s += psum[o * 256 + k];
    q += psq[o * 256 + k];
  }
  const float inv = 1.0f / 524288.0f;
  float m = s * inv;
  float ey2 = q * inv;
  float v = fmaf(-m, m, ey2);
  v = fmaxf(v, 0.f);
  float r = rsqrtf(v + EPSV);
  float a = g[o] * r;
  sc[o] = a;
  sh[o] = fmaf(-m, a, be[o]);
}

// out[b, o, s] = relu(a*sel + c), sel = max if a>=0 else min
__global__ __launch_bounds__(256) void k_out(const float* __restrict__ maxb, const float* __restrict__ minb,
                                             const float* __restrict__ sc, const float* __restrict__ sh,
                                             float* __restrict__ out) {
  int flat = blockIdx.x * 256 + threadIdx.x;  // 2,097,152
  int b = flat >> 18;
  int o = (flat >> 10) & 255;
  int s = flat & 1023;
  float a = sc[o], c_ = sh[o];
  size_t mi = ((size_t)(b * 1024 + s)) * 256 + o;
  float v = (a >= 0.f) ? maxb[mi] : minb[mi];
  out[OUT_FEAT + flat] = fmaxf(fmaf(a, v, c_), 0.f);
}

extern "C" void kernel_launch(void* const* d_in, const int* in_sizes, int n_in,
                              void* d_out, int out_size, void* d_ws, size_t ws_size,
                              hipStream_t stream) {
  const float* xyz = (const float*)d_in[0];
  const float* pts = (const float*)d_in[1];
  const int* fps = (const int*)d_in[2];
  const float* W0 = (const float*)d_in[3];
  const float* b0 = (const float*)d_in[4];
  const float* g0 = (const float*)d_in[5];
  const float* be0 = (const float*)d_in[6];
  const float* W1 = (const float*)d_in[7];
  const float* b1 = (const float*)d_in[8];
  const float* g1 = (const float*)d_in[9];
  const float* be1 = (const float*)d_in[10];
  const float* W2 = (const float*)d_in[11];
  const float* b2 = (const float*)d_in[12];
  const float* g2 = (const float*)d_in[13];
  const float* be2 = (const float*)d_in[14];
  float* out = (float*)d_out;
  char* ws = (char*)d_ws;

  // new_xyz and fps passthrough need no workspace — always produce them so an
  // undersized ws shows up as "output 1 wrong, outputs 0/2 right".
  k_newxyz<<<32, 256, 0, stream>>>(xyz, fps, out);
  if (ws_size < WS_NEEDED) return;

  _Float16* ptsT = (_Float16*)(ws + O_PT);
  _Float16* y0 = (_Float16*)(ws + O_Y0);
  _Float16* y1 = (_Float16*)(ws + O_Y1);
  int* idxb = (int*)(ws + O_IDX);
  float* maxbf = (float*)(ws + O_MAXB);
  float* minbf = (float*)(ws + O_MINB);
  _Float16* W0h = (_Float16*)(ws + O_W0T);
  _Float16* W1h = (_Float16*)(ws + O_W1T);
  _Float16* W2h = (_Float16*)(ws + O_W2T);
  float* ps0 = (float*)(ws + O_PS0);
  float* pq0 = (float*)(ws + O_PQ0);
  float* ps1 = (float*)(ws + O_PS1);
  float* pq1 = (float*)(ws + O_PQ1);
  float* ps2 = (float*)(ws + O_PS2);
  float* pq2 = (float*)(ws + O_PQ2);
  float* sc0 = (float*)(ws + O_SC0);
  float* sh0 = (float*)(ws + O_SH0);
  float* sc1 = (float*)(ws + O_SC1);
  float* sh1 = (float*)(ws + O_SH1);
  float* sc2 = (float*)(ws + O_SC2);
  float* sh2 = (float*)(ws + O_SH2);

  hipMemsetAsync(ws + O_PS0, 0, PART_BYTES, stream);
  k_transpose_pts<<<dim3(NN / 32, DD / 32, BB), dim3(32, 8), 0, stream>>>(pts, ptsT);
  k_wt<<<272, 256, 0, stream>>>(W0, W1, W2, W0h, W1h, W2h);
  k_ballq<<<2048, 256, 0, stream>>>(xyz, fps, idxb);
  k_mlp0<<<8192, 256, 0, stream>>>(xyz, ptsT, fps, idxb, W0h, b0, y0, ps0, pq0);
  k_fin<<<1, 256, 0, stream>>>(ps0, pq0, g0, be0, sc0, sh0, 128);
  k_mlp1<<<8192, 256, 0, stream>>>(y0, sc0, sh0, W1h, b1, y1, ps1, pq1);
  k_fin<<<1, 256, 0, stream>>>(ps1, pq1, g1, be1, sc1, sh1, 128);
  k_mlp2<<<8192, 256, 0, stream>>>(y1, sc1, sh1, W2h, b2, maxbf, minbf, ps2, pq2);
  k_fin<<<1, 256, 0, stream>>>(ps2, pq2, g2, be2, sc2, sh2, 256);
  k_out<<<8192, 256, 0, stream>>>(maxbf, minbf, sc2, sh2, out);
}

// Round 2
// 114.343 us; speedup vs baseline: 1.0217x; 1.0217x over previous
//
#include <hip/hip_runtime.h>
#include <hip/hip_bf16.h>

#define BB 8
#define NN 16384
#define SS 1024
#define NSMP 64
#define DD 128
#define R2 0.04f
#define EPSV 1e-5f

typedef _Float16 half2t __attribute__((ext_vector_type(2)));
typedef _Float16 half8t __attribute__((ext_vector_type(8)));
typedef float f32x4 __attribute__((ext_vector_type(4)));

// ---- workspace layout (bytes) ----  (y0/y1 slots retained but unused)
#define O_PT    0ull                 // pointsT fp16: 8*16384*128*2 = 33,554,432
#define O_IDX   301989888ull         // idx int32: 8192*64*4 = 2,097,152
#define O_MAXB  304087040ull         // 8192*256*4 = 8,388,608
#define O_MINB  312475648ull         // 8,388,608
#define O_W0T   320864256ull         // W0h fp16 [128][136] = 34,816
#define O_W1T   320931328ull         // W1h fp16 [128][136] = 34,816
#define O_W2T   320996864ull         // W2h fp16 [256][136] = 69,632
#define O_PS0   321127936ull         // 128*256*4 = 131,072  (zero region starts here, 1MB)
#define O_PQ0   321259008ull
#define O_PS1   321390080ull
#define O_PQ1   321521152ull
#define O_PS2   321652224ull         // 256*256*4 = 262,144
#define O_PQ2   321914368ull
#define O_SC0   322176512ull
#define O_SH0   322177024ull
#define O_SC1   322177536ull
#define O_SH1   322178048ull
#define O_SC2   322178560ull
#define O_SH2   322179584ull
#define WS_NEEDED 322180608ull

#define OUT_XYZ 0
#define OUT_FEAT 24576
#define OUT_FPS (24576 + 2097152)

// points [B,D,N] fp32 -> pointsT [B,N,D] fp16
__global__ __launch_bounds__(256) void k_transpose_pts(const float* __restrict__ pts,
                                                       _Float16* __restrict__ ptsT) {
  __shared__ float tile[32][33];
  int b = blockIdx.z;
  int n0 = blockIdx.x * 32, c0 = blockIdx.y * 32;
  int tx = threadIdx.x, ty = threadIdx.y;
#pragma unroll
  for (int k = 0; k < 4; k++) {
    int c = c0 + ty + k * 8;
    tile[ty + k * 8][tx] = pts[((size_t)b * DD + c) * NN + n0 + tx];
  }
  __syncthreads();
#pragma unroll
  for (int k = 0; k < 4; k++) {
    int n = n0 + ty + k * 8;
    ptsT[((size_t)b * NN + n) * DD + c0 + tx] = (_Float16)tile[tx][ty + k * 8];
  }
}

// weights -> fp16, [out][in] stride 136, zero-padded; also zeroes the 1MB stats region.
// W0 channels remapped: xh has feats at c=0..127, relxyz at 128..130
__global__ __launch_bounds__(256) void k_wt(const float* __restrict__ W0, const float* __restrict__ W1,
                                            const float* __restrict__ W2, _Float16* __restrict__ W0h,
                                            _Float16* __restrict__ W1h, _Float16* __restrict__ W2h,
                                            float* __restrict__ zreg) {
  int id = blockIdx.x * 256 + threadIdx.x;
  // zero 1MB stats region: 65536 float4
  if (id < 65536) {
    f32x4 z = {0.f, 0.f, 0.f, 0.f};
    ((f32x4*)zreg)[id] = z;
  }
  const int T0 = 128 * 136, T1 = 128 * 136, T2 = 256 * 136;
  if (id < T0) {
    int o = id / 136, c = id % 136;
    float v = 0.f;
    if (c < 131) {
      int c0 = (c < 128) ? (c + 3) : (c - 128);
      v = W0[o * 131 + c0];
    }
    W0h[id] = (_Float16)v;
  } else if (id < T0 + T1) {
    int j = id - T0;
    int o = j / 136, c = j % 136;
    W1h[j] = (_Float16)((c < 128) ? W1[o * 128 + c] : 0.f);
  } else if (id < T0 + T1 + T2) {
    int j = id - T0 - T1;
    int o = j / 136, c = j % 136;
    W2h[j] = (_Float16)((c < 128) ? W2[o * 128 + c] : 0.f);
  }
}

// fallback when workspace undersized
__global__ __launch_bounds__(256) void k_newxyz(const float* __restrict__ xyz, const int* __restrict__ fps,
                                                float* __restrict__ out) {
  int id = blockIdx.x * 256 + threadIdx.x;  // B*S
  int fi = fps[id];
  int b = id >> 10;
  const float* p = xyz + ((size_t)b * NN + fi) * 3;
  float* o = out + OUT_XYZ + (size_t)id * 3;
  o[0] = p[0]; o[1] = p[1]; o[2] = p[2];
  out[OUT_FPS + id] = (float)fi;
}

// one wave per (b,s): first-NS valid indices ascending, pad with first valid.
// Also emits new_xyz and fps passthrough outputs (fused k_newxyz).
__global__ __launch_bounds__(256) void k_ballq(const float* __restrict__ xyz, const int* __restrict__ fps,
                                               int* __restrict__ idxb, float* __restrict__ out) {
  int w = (blockIdx.x * 256 + threadIdx.x) >> 6;
  int lane = threadIdx.x & 63;
  int b = w >> 10;
  int fi = fps[w];
  const float* cp = xyz + ((size_t)b * NN + fi) * 3;
  float cx = cp[0], cy = cp[1], cz = cp[2];
  if (lane < 3) out[OUT_XYZ + (size_t)w * 3 + lane] = (lane == 0) ? cx : ((lane == 1) ? cy : cz);
  if (lane == 3) out[OUT_FPS + w] = (float)fi;
  // match numpy association: (cx^2 + cy^2) + cz^2
  float A = __fadd_rn(__fadd_rn(__fmul_rn(cx, cx), __fmul_rn(cy, cy)), __fmul_rn(cz, cz));
  const float* xb = xyz + (size_t)b * NN * 3;
  int cnt = 0, firstn = -1;
  int* myidx = idxb + (size_t)w * NSMP;
  for (int nb = 0; nb < NN && cnt < NSMP; nb += 64) {
    int n = nb + lane;
    float px = xb[n * 3], py = xb[n * 3 + 1], pz = xb[n * 3 + 2];
    float Bv = __fadd_rn(__fadd_rn(__fmul_rn(px, px), __fmul_rn(py, py)), __fmul_rn(pz, pz));
    float dot = __fadd_rn(__fadd_rn(__fmul_rn(cx, px), __fmul_rn(cy, py)), __fmul_rn(cz, pz));
    float d = __fsub_rn(__fadd_rn(A, Bv), __fmul_rn(2.0f, dot));
    bool valid = !(d > R2);
    unsigned long long mask = __ballot(valid);
    if (firstn < 0 && mask) firstn = nb + __builtin_ctzll(mask);
    int prefix = __popcll(mask & ((1ull << lane) - 1ull));
    int pos = cnt + prefix;
    if (valid && pos < NSMP) myidx[pos] = n;
    cnt += __popcll(mask);
    if (cnt > NSMP) cnt = NSMP;
  }
  if (lane >= cnt) myidx[lane] = firstn;
}

// ---------- shared device pieces for the fused MLP passes ----------

// gather ball rows into xh[64][136] fp16 (feats 0..127, relxyz 128..130)
__device__ __forceinline__ void load_ball(const float* __restrict__ xyz,
                                          const _Float16* __restrict__ ptsT,
                                          const int* __restrict__ fps, const int* __restrict__ idxb,
                                          int bs, int b, int t, _Float16* xh, int* smidx, float* smc) {
  if (t < 64) smidx[t] = idxb[(size_t)bs * 64 + t];
  if (t < 3) {
    int fi = fps[bs];
    smc[t] = xyz[((size_t)b * NN + fi) * 3 + t];
  }
  __syncthreads();
  {
    int row = t >> 2, q = t & 3;
    int n = smidx[row];
    const half8t* src = (const half8t*)(ptsT + ((size_t)b * NN + n) * DD);
#pragma unroll
    for (int i = 0; i < 4; i++) {
      int j = q + i * 4;
      *(half8t*)(xh + row * 136 + j * 8) = src[j];
    }
  }
  if (t < 64) {
    int n = smidx[t];
    const float* p = xyz + ((size_t)b * NN + n) * 3;
    xh[t * 136 + 128] = (_Float16)(p[0] - smc[0]);
    xh[t * 136 + 129] = (_Float16)(p[1] - smc[1]);
    xh[t * 136 + 130] = (_Float16)(p[2] - smc[2]);
  }
  __syncthreads();
}

// layer0 MFMA (K=128 via matrix core + 3 relxyz channels on VALU)
__device__ __forceinline__ void mfma_l0(const _Float16* xh, const _Float16* __restrict__ W0h,
                                        const float* __restrict__ b0, int m0, int lr, int lk,
                                        f32x4* acc) {
  half8t afr[4];
#pragma unroll
  for (int kt = 0; kt < 4; kt++)
    afr[kt] = *(const half8t*)(xh + (m0 + lr) * 136 + kt * 32 + lk * 8);
#pragma unroll
  for (int nt = 0; nt < 8; nt++) {
    float bv = b0[nt * 16 + lr];
    f32x4 cv = {bv, bv, bv, bv};
    acc[nt] = cv;
  }
#pragma unroll
  for (int kt = 0; kt < 4; kt++) {
#pragma unroll
    for (int nt = 0; nt < 8; nt++) {
      half8t bw = *(const half8t*)(W0h + (nt * 16 + lr) * 136 + kt * 32 + lk * 8);
      acc[nt] = __builtin_amdgcn_mfma_f32_16x16x32_f16(afr[kt], bw, acc[nt], 0, 0, 0);
    }
  }
  float xr[4][3];
#pragma unroll
  for (int r = 0; r < 4; r++) {
    int m = m0 + lk * 4 + r;
    xr[r][0] = (float)xh[m * 136 + 128];
    xr[r][1] = (float)xh[m * 136 + 129];
    xr[r][2] = (float)xh[m * 136 + 130];
  }
#pragma unroll
  for (int nt = 0; nt < 8; nt++) {
    const _Float16* wp = W0h + (nt * 16 + lr) * 136 + 128;
    float w0 = (float)wp[0], w1 = (float)wp[1], w2 = (float)wp[2];
#pragma unroll
    for (int r = 0; r < 4; r++)
      acc[nt][r] += xr[r][0] * w0 + xr[r][1] * w1 + xr[r][2] * w2;
  }
}

// generic K=128 layer: NT output groups of 16
template <int NT>
__device__ __forceinline__ void mfma_lx(const _Float16* xh, const _Float16* __restrict__ Wh,
                                        const float* __restrict__ bias, int m0, int lr, int lk,
                                        f32x4* acc) {
  half8t afr[4];
#pragma unroll
  for (int kt = 0; kt < 4; kt++)
    afr[kt] = *(const half8t*)(xh + (m0 + lr) * 136 + kt * 32 + lk * 8);
#pragma unroll
  for (int nt = 0; nt < NT; nt++) {
    float bv = bias[nt * 16 + lr];
    f32x4 cv = {bv, bv, bv, bv};
    acc[nt] = cv;
  }
#pragma unroll
  for (int kt = 0; kt < 4; kt++) {
#pragma unroll
    for (int nt = 0; nt < NT; nt++) {
      half8t bw = *(const half8t*)(Wh + (nt * 16 + lr) * 136 + kt * 32 + lk * 8);
      acc[nt] = __builtin_amdgcn_mfma_f32_16x16x32_f16(afr[kt], bw, acc[nt], 0, 0, 0);
    }
  }
}

// affine+relu applied to acc (D-layout), written to xh fp16 as next layer's input
__device__ __forceinline__ void store_act(_Float16* xh, const float* __restrict__ sc,
                                          const float* __restrict__ sh, int m0, int lr, int lk,
                                          const f32x4* acc) {
#pragma unroll
  for (int nt = 0; nt < 8; nt++) {
    int col = nt * 16 + lr;
    float a = sc[col], c = sh[col];
#pragma unroll
    for (int r = 0; r < 4; r++) {
      float v = fmaxf(fmaf(acc[nt][r], a, c), 0.f);
      xh[(m0 + lk * 4 + r) * 136 + col] = (_Float16)v;
    }
  }
}

__device__ __forceinline__ void dump_xs(float* xs, const f32x4* acc, int m0, int lr, int lk) {
#pragma unroll
  for (int nt = 0; nt < 8; nt++)
#pragma unroll
    for (int r = 0; r < 4; r++)
      xs[(m0 + lk * 4 + r) * 133 + nt * 16 + lr] = acc[nt][r];
}

__device__ __forceinline__ void stats_epilogue(const float* xs, float* rbuf,
                                               float* __restrict__ psum, float* __restrict__ psq,
                                               int t, int bs) {
  int col = t & 127, hf = t >> 7;
  float s = 0.f, q = 0.f;
#pragma unroll 4
  for (int r = hf * 32; r < hf * 32 + 32; r++) {
    float v = xs[r * 133 + col];
    s += v;
    q = fmaf(v, v, q);
  }
  if (hf) { rbuf[col * 2] = s; rbuf[col * 2 + 1] = q; }
  __syncthreads();
  if (!hf) {
    s += rbuf[col * 2];
    q += rbuf[col * 2 + 1];
    int slot = bs & 255;
    atomicAdd(&psum[col * 256 + slot], s);
    atomicAdd(&psq[col * 256 + slot], q);
  }
}

// ---------- fused passes (no y0/y1 materialization) ----------

// K1: gather -> L0 -> stats0
__global__ __launch_bounds__(256, 2) void k_pass1(const float* __restrict__ xyz,
                                                  const _Float16* __restrict__ ptsT,
                                                  const int* __restrict__ fps, const int* __restrict__ idxb,
                                                  const _Float16* __restrict__ W0h, const float* __restrict__ b0,
                                                  float* __restrict__ psum, float* __restrict__ psq) {
  __shared__ _Float16 xh[64 * 136];
  __shared__ float xs[64 * 133];
  __shared__ float rbuf[128 * 2];
  __shared__ int smidx[64];
  __shared__ float smc[3];
  int t = threadIdx.x;
  int bs = blockIdx.x;
  int b = bs >> 10;
  load_ball(xyz, ptsT, fps, idxb, bs, b, t, xh, smidx, smc);
  int lane = t & 63;
  int m0 = __builtin_amdgcn_readfirstlane((t >> 6) * 16);
  int lr = lane & 15, lk = lane >> 4;
  f32x4 acc[8];
  mfma_l0(xh, W0h, b0, m0, lr, lk, acc);
  dump_xs(xs, acc, m0, lr, lk);
  __syncthreads();
  stats_epilogue(xs, rbuf, psum, psq, t, bs);
}

// K2: gather -> L0 -> aff0+relu -> L1 -> stats1
__global__ __launch_bounds__(256, 2) void k_pass2(const float* __restrict__ xyz,
                                                  const _Float16* __restrict__ ptsT,
                                                  const int* __restrict__ fps, const int* __restrict__ idxb,
                                                  const _Float16* __restrict__ W0h, const float* __restrict__ b0,
                                                  const float* __restrict__ sc0, const float* __restrict__ sh0,
                                                  const _Float16* __restrict__ W1h, const float* __restrict__ b1,
                                                  float* __restrict__ psum, float* __restrict__ psq) {
  __shared__ _Float16 xh[64 * 136];
  __shared__ float xs[64 * 133];
  __shared__ float rbuf[128 * 2];
  __shared__ int smidx[64];
  __shared__ float smc[3];
  int t = threadIdx.x;
  int bs = blockIdx.x;
  int b = bs >> 10;
  load_ball(xyz, ptsT, fps, idxb, bs, b, t, xh, smidx, smc);
  int lane = t & 63;
  int m0 = __builtin_amdgcn_readfirstlane((t >> 6) * 16);
  int lr = lane & 15, lk = lane >> 4;
  f32x4 acc[8];
  mfma_l0(xh, W0h, b0, m0, lr, lk, acc);
  __syncthreads();  // all waves done reading xh
  store_act(xh, sc0, sh0, m0, lr, lk, acc);
  __syncthreads();
  mfma_lx<8>(xh, W1h, b1, m0, lr, lk, acc);
  dump_xs(xs, acc, m0, lr, lk);
  __syncthreads();
  stats_epilogue(xs, rbuf, psum, psq, t, bs);
}

// K3: gather -> L0 -> aff0 -> L1 -> aff1 -> L2 -> max/min + stats2
__global__ __launch_bounds__(256, 2) void k_pass3(const float* __restrict__ xyz,
                                                  const _Float16* __restrict__ ptsT,
                                                  const int* __restrict__ fps, const int* __restrict__ idxb,
                                                  const _Float16* __restrict__ W0h, const float* __restrict__ b0,
                                                  const float* __restrict__ sc0, const float* __restrict__ sh0,
                                                  const _Float16* __restrict__ W1h, const float* __restrict__ b1,
                                                  const float* __restrict__ sc1, const float* __restrict__ sh1,
                                                  const _Float16* __restrict__ W2h, const float* __restrict__ b2,
                                                  float* __restrict__ maxb, float* __restrict__ minb,
                                                  float* __restrict__ psum, float* __restrict__ psq) {
  __shared__ _Float16 xh[64 * 136];
  __shared__ float xs[64 * 133];
  __shared__ float rbuf[128 * 4];
  __shared__ int smidx[64];
  __shared__ float smc[3];
  int t = threadIdx.x;
  int bs = blockIdx.x;
  int b = bs >> 10;
  load_ball(xyz, ptsT, fps, idxb, bs, b, t, xh, smidx, smc);
  int lane = t & 63;
  int m0 = __builtin_amdgcn_readfirstlane((t >> 6) * 16);
  int lr = lane & 15, lk = lane >> 4;
  f32x4 acc[8];
  mfma_l0(xh, W0h, b0, m0, lr, lk, acc);
  __syncthreads();
  store_act(xh, sc0, sh0, m0, lr, lk, acc);
  __syncthreads();
  mfma_lx<8>(xh, W1h, b1, m0, lr, lk, acc);
  __syncthreads();
  store_act(xh, sc1, sh1, m0, lr, lk, acc);
  __syncthreads();
  f32x4 acc2[16];
  mfma_lx<16>(xh, W2h, b2, m0, lr, lk, acc2);
  // two 128-col phases through xs
  for (int ph = 0; ph < 2; ph++) {
#pragma unroll
    for (int nt = 0; nt < 8; nt++)
#pragma unroll
      for (int r = 0; r < 4; r++)
        xs[(m0 + lk * 4 + r) * 133 + nt * 16 + lr] = acc2[ph * 8 + nt][r];
    __syncthreads();
    {
      int col = t & 127, hf = t >> 7;
      float s = 0.f, q = 0.f, mx = -3.4e38f, mn = 3.4e38f;
#pragma unroll 4
      for (int r = hf * 32; r < hf * 32 + 32; r++) {
        float v = xs[r * 133 + col];
        s += v;
        q = fmaf(v, v, q);
        mx = fmaxf(mx, v);
        mn = fminf(mn, v);
      }
      if (hf) {
        rbuf[col * 4] = s; rbuf[col * 4 + 1] = q;
        rbuf[col * 4 + 2] = mx; rbuf[col * 4 + 3] = mn;
      }
      __syncthreads();
      if (!hf) {
        s += rbuf[col * 4];
        q += rbuf[col * 4 + 1];
        mx = fmaxf(mx, rbuf[col * 4 + 2]);
        mn = fminf(mn, rbuf[col * 4 + 3]);
        int o = ph * 128 + col;
        maxb[(size_t)bs * 256 + o] = mx;
        minb[(size_t)bs * 256 + o] = mn;
        int slot = bs & 255;
        atomicAdd(&psum[o * 256 + slot], s);
        atomicAdd(&psq[o * 256 + slot], q);
      }
    }
    __syncthreads();
  }
}

// fold BN stats into per-channel affine: a = g*rsqrt(var+eps); c = be - mean*a
__global__ __launch_bounds__(256) void k_fin(const float* __restrict__ psum, const float* __restrict__ psq,
                                             const float* __restrict__ g, const float* __restrict__ be,
                                             float* __restrict__ sc, float* __restrict__ sh, int nch) {
  int o = threadIdx.x;
  if (o >= nch) return;
  float s = 0.f, q = 0.f;
  for (int k = 0; k < 256; k++) {
    s += psum[o * 256 + k];
    q += psq[o * 256 + k];
  }
  const float inv = 1.0f / 524288.0f;
  float m = s * inv;
  float ey2 = q * inv;
  float v = fmaf(-m, m, ey2);
  v = fmaxf(v, 0.f);
  float r = rsqrtf(v + EPSV);
  float a = g[o] * r;
  sc[o] = a;
  sh[o] = fmaf(-m, a, be[o]);
}

// out[b, o, s] = relu(a*sel + c), sel = max if a>=0 else min
__global__ __launch_bounds__(256) void k_out(const float* __restrict__ maxb, const float* __restrict__ minb,
                                             const float* __restrict__ sc, const float* __restrict__ sh,
                                             float* __restrict__ out) {
  int flat = blockIdx.x * 256 + threadIdx.x;  // 2,097,152
  int b = flat >> 18;
  int o = (flat >> 10) & 255;
  int s = flat & 1023;
  float a = sc[o], c_ = sh[o];
  size_t mi = ((size_t)(b * 1024 + s)) * 256 + o;
  float v = (a >= 0.f) ? maxb[mi] : minb[mi];
  out[OUT_FEAT + flat] = fmaxf(fmaf(a, v, c_), 0.f);
}

extern "C" void kernel_launch(void* const* d_in, const int* in_sizes, int n_in,
                              void* d_out, int out_size, void* d_ws, size_t ws_size,
                              hipStream_t stream) {
  const float* xyz = (const float*)d_in[0];
  const float* pts = (const float*)d_in[1];
  const int* fps = (const int*)d_in[2];
  const float* W0 = (const float*)d_in[3];
  const float* b0 = (const float*)d_in[4];
  const float* g0 = (const float*)d_in[5];
  const float* be0 = (const float*)d_in[6];
  const float* W1 = (const float*)d_in[7];
  const float* b1 = (const float*)d_in[8];
  const float* g1 = (const float*)d_in[9];
  const float* be1 = (const float*)d_in[10];
  const float* W2 = (const float*)d_in[11];
  const float* b2 = (const float*)d_in[12];
  const float* g2 = (const float*)d_in[13];
  const float* be2 = (const float*)d_in[14];
  float* out = (float*)d_out;
  char* ws = (char*)d_ws;

  if (ws_size < WS_NEEDED) {
    k_newxyz<<<32, 256, 0, stream>>>(xyz, fps, out);
    return;
  }

  _Float16* ptsT = (_Float16*)(ws + O_PT);
  int* idxb = (int*)(ws + O_IDX);
  float* maxbf = (float*)(ws + O_MAXB);
  float* minbf = (float*)(ws + O_MINB);
  _Float16* W0h = (_Float16*)(ws + O_W0T);
  _Float16* W1h = (_Float16*)(ws + O_W1T);
  _Float16* W2h = (_Float16*)(ws + O_W2T);
  float* ps0 = (float*)(ws + O_PS0);
  float* pq0 = (float*)(ws + O_PQ0);
  float* ps1 = (float*)(ws + O_PS1);
  float* pq1 = (float*)(ws + O_PQ1);
  float* ps2 = (float*)(ws + O_PS2);
  float* pq2 = (float*)(ws + O_PQ2);
  float* sc0 = (float*)(ws + O_SC0);
  float* sh0 = (float*)(ws + O_SH0);
  float* sc1 = (float*)(ws + O_SC1);
  float* sh1 = (float*)(ws + O_SH1);
  float* sc2 = (float*)(ws + O_SC2);
  float* sh2 = (float*)(ws + O_SH2);

  k_transpose_pts<<<dim3(NN / 32, DD / 32, BB), dim3(32, 8), 0, stream>>>(pts, ptsT);
  k_wt<<<272, 256, 0, stream>>>(W0, W1, W2, W0h, W1h, W2h, ps0);
  k_ballq<<<2048, 256, 0, stream>>>(xyz, fps, idxb, out);
  k_pass1<<<8192, 256, 0, stream>>>(xyz, ptsT, fps, idxb, W0h, b0, ps0, pq0);
  k_fin<<<1, 256, 0, stream>>>(ps0, pq0, g0, be0, sc0, sh0, 128);
  k_pass2<<<8192, 256, 0, stream>>>(xyz, ptsT, fps, idxb, W0h, b0, sc0, sh0, W1h, b1, ps1, pq1);
  k_fin<<<1, 256, 0, stream>>>(ps1, pq1, g1, be1, sc1, sh1, 128);
  k_pass3<<<8192, 256, 0, stream>>>(xyz, ptsT, fps, idxb, W0h, b0, sc0, sh0, W1h, b1, sc1, sh1,
                                    W2h, b2, maxbf, minbf, ps2, pq2);
  k_fin<<<1, 256, 0, stream>>>(ps2, pq2, g2, be2, sc2, sh2, 256);
  k_out<<<8192, 256, 0, stream>>>(maxbf, minbf, sc2, sh2, out);
}